// Round 1
// 2211.787 us; speedup vs baseline: 1.0111x; 1.0111x over previous
//
#include <hip/hip_runtime.h>
#include <cstddef>

#define NCELL 100000
#define NNZE  800000
#define HID   128
#define CIN   64
#define T7    (7 * NCELL)

struct P7i { const int* p[7]; };
struct P7f { const float* p[7]; };

__device__ __forceinline__ unsigned short f2bf(float f) {
  unsigned u = __float_as_uint(f);
  return (unsigned short)((u + 0x7fffu + ((u >> 16) & 1u)) >> 16);
}
__device__ __forceinline__ float bflo(unsigned x) { return __uint_as_float(x << 16); }
__device__ __forceinline__ float bfhi(unsigned x) { return __uint_as_float(x & 0xffff0000u); }
__device__ __forceinline__ void fma4(float4& a, float s, const float4& w) {
  a.x += s * w.x; a.y += s * w.y; a.z += s * w.z; a.w += s * w.w;
}

// ============================ CSR build (fused, all 7) ==================
__global__ __launch_bounds__(256) void hist_all(P7i keys, int* __restrict__ counts) {
  int s = blockIdx.y;
  int i = blockIdx.x * 256 + threadIdx.x;
  if (i < NNZE) atomicAdd(&counts[s * NCELL + keys.p[s][i]], 1);
}

// chunk = 16384 per block; 43 blocks cover 700000
__global__ __launch_bounds__(256) void scan_partial2(const int* __restrict__ counts,
                                                     int* __restrict__ bsum) {
  __shared__ int sdata[256];
  int t = threadIdx.x;
  int s = 0;
  for (int j = 0; j < 64; ++j) {
    int i = blockIdx.x * 16384 + j * 256 + t;
    if (i < T7) s += counts[i];
  }
  sdata[t] = s;
  __syncthreads();
  for (int off = 128; off > 0; off >>= 1) {
    if (t < off) sdata[t] += sdata[t + off];
    __syncthreads();
  }
  if (t == 0) bsum[blockIdx.x] = sdata[0];
}

__global__ __launch_bounds__(64) void scan_bsum(int* __restrict__ bsum, int nblk) {
  int l = threadIdx.x;
  int orig = (l < nblk) ? bsum[l] : 0;
  int v = orig;
  for (int off = 1; off < 64; off <<= 1) {
    int w = __shfl_up(v, off);
    if (l >= off) v += w;
  }
  if (l < nblk) bsum[l] = v - orig;  // exclusive
}

__global__ __launch_bounds__(256) void scan_final2(const int* __restrict__ counts,
                                                   const int* __restrict__ bsum,
                                                   int* __restrict__ rowp,
                                                   int* __restrict__ cursor) {
  __shared__ int ss[256];
  int t = threadIdx.x;
  int base = blockIdx.x * 16384 + t * 64;
  int ts = 0;
  for (int j = 0; j < 64; ++j) {
    int i = base + j;
    if (i < T7) ts += counts[i];
  }
  ss[t] = ts;
  __syncthreads();
  for (int off = 1; off < 256; off <<= 1) {
    int v = (t >= off) ? ss[t - off] : 0;
    __syncthreads();
    ss[t] += v;
    __syncthreads();
  }
  int offset = bsum[blockIdx.x] + ss[t] - ts;
  for (int j = 0; j < 64; ++j) {
    int i = base + j;
    if (i < T7) {
      rowp[i] = offset;
      cursor[i] = offset;
      offset += counts[i];
    }
  }
  if (blockIdx.x == 0 && t == 0) rowp[T7] = 7 * NNZE;
}

// (col,val) paired into one int2: one random 8B store per nnz instead of
// two random 4B stores into two arrays -> half the dirty L2 lines.
__global__ __launch_bounds__(256) void scatter_all(P7i keys, P7i oth, P7f vs,
                                                   int* __restrict__ cursor,
                                                   int2* __restrict__ ocv) {
  int s = blockIdx.y;
  int i = blockIdx.x * 256 + threadIdx.x;
  if (i < NNZE) {
    int k = keys.p[s][i];
    int pos = atomicAdd(&cursor[s * NCELL + k], 1);
    ocv[pos] = make_int2(oth.p[s][i], __float_as_int(vs.p[s][i]));
  }
}

// ============================ SpMM width-256 (bf16 gathers) =============
// one wave per row; lane owns 4 bf16 cols (8B). MODE: 0=write bf16 outT,
// 1=write fp32 comb split by encoder, 2=accumulate 0.5x into comb split,
// 3=final accumulate + fused sigmoid gate + mean-write into h buffers.
template <int MODE>
__global__ __launch_bounds__(256) void spmm256(const int* __restrict__ rowp,
                                               const int2* __restrict__ cv,
                                               const uint2* __restrict__ xb,
                                               uint2* __restrict__ outT,
                                               float4* __restrict__ c0,
                                               float4* __restrict__ c1,
                                               const float4* __restrict__ g0p,
                                               const float4* __restrict__ g1p,
                                               float4* __restrict__ hon,
                                               float4* __restrict__ htg,
                                               int first) {
  int wid = (blockIdx.x * 256 + threadIdx.x) >> 6;
  int lane = threadIdx.x & 63;
  int s = rowp[wid], e = rowp[wid + 1];
  float a0 = 0.f, a1 = 0.f, a2 = 0.f, a3 = 0.f;
  int i = s;
  for (; i + 4 <= e; i += 4) {
    int2 p0 = cv[i], p1 = cv[i + 1], p2 = cv[i + 2], p3 = cv[i + 3];
    float v0 = __int_as_float(p0.y), v1 = __int_as_float(p1.y);
    float v2 = __int_as_float(p2.y), v3 = __int_as_float(p3.y);
    uint2 g0 = xb[(size_t)p0.x * 64 + lane];
    uint2 g1 = xb[(size_t)p1.x * 64 + lane];
    uint2 g2 = xb[(size_t)p2.x * 64 + lane];
    uint2 g3 = xb[(size_t)p3.x * 64 + lane];
    a0 += v0 * bflo(g0.x); a1 += v0 * bfhi(g0.x); a2 += v0 * bflo(g0.y); a3 += v0 * bfhi(g0.y);
    a0 += v1 * bflo(g1.x); a1 += v1 * bfhi(g1.x); a2 += v1 * bflo(g1.y); a3 += v1 * bfhi(g1.y);
    a0 += v2 * bflo(g2.x); a1 += v2 * bfhi(g2.x); a2 += v2 * bflo(g2.y); a3 += v2 * bfhi(g2.y);
    a0 += v3 * bflo(g3.x); a1 += v3 * bfhi(g3.x); a2 += v3 * bflo(g3.y); a3 += v3 * bfhi(g3.y);
  }
  for (; i < e; ++i) {
    int2 p = cv[i];
    float v = __int_as_float(p.y);
    uint2 g = xb[(size_t)p.x * 64 + lane];
    a0 += v * bflo(g.x); a1 += v * bfhi(g.x); a2 += v * bflo(g.y); a3 += v * bfhi(g.y);
  }
  if (MODE == 0) {
    uint2 pk;
    pk.x = (unsigned)f2bf(a0) | ((unsigned)f2bf(a1) << 16);
    pk.y = (unsigned)f2bf(a2) | ((unsigned)f2bf(a3) << 16);
    outT[(size_t)wid * 64 + lane] = pk;
  } else if (MODE == 1 || MODE == 2) {
    float4 v = make_float4(a0, a1, a2, a3);
    float4* dst = (lane < 32) ? (c0 + (size_t)wid * 32 + lane)
                              : (c1 + (size_t)wid * 32 + (lane - 32));
    if (MODE == 1) {
      *dst = v;
    } else {
      float4 cur = *dst;
      cur.x += 0.5f * v.x; cur.y += 0.5f * v.y;
      cur.z += 0.5f * v.z; cur.w += 0.5f * v.w;
      *dst = cur;
    }
  } else {  // MODE 3: final accumulate + gate, comb never written back
    bool e1 = lane >= 32;
    int l = lane & 31;
    const float4* cb = e1 ? c1 : c0;
    float4 cur = cb[(size_t)wid * 32 + l];
    cur.x += 0.5f * a0; cur.y += 0.5f * a1;
    cur.z += 0.5f * a2; cur.w += 0.5f * a3;
    float4 avv = (e1 ? g1p : g0p)[l];
    float d = cur.x * avv.x + cur.y * avv.y + cur.z * avv.z + cur.w * avv.w;
    d += __shfl_xor(d, 16);
    d += __shfl_xor(d, 8);
    d += __shfl_xor(d, 4);
    d += __shfl_xor(d, 2);
    d += __shfl_xor(d, 1);
    float g = (1.f / (1.f + __expf(-d))) * (1.f / 3.f);
    float4* hb = e1 ? htg : hon;
    size_t oi = (size_t)wid * 32 + l;
    float4 v = make_float4(g * cur.x, g * cur.y, g * cur.z, g * cur.w);
    if (first) {
      hb[oi] = v;
    } else {
      float4 c = hb[oi];
      c.x += v.x; c.y += v.y; c.z += v.z; c.w += v.w;
      hb[oi] = c;
    }
  }
}

// ===================== fused input GEMM (both encoders) =================
// xt2[n][256] (bf16) = [ x[n]@W0+b0 | x[n]@W1+b1 ] ; 16 rows/block
__global__ __launch_bounds__(256) void gemm_nc2(const float* __restrict__ x,
                                                const float* __restrict__ W0,
                                                const float* __restrict__ b0,
                                                const float* __restrict__ W1,
                                                const float* __restrict__ b1,
                                                uint2* __restrict__ out) {
  __shared__ float xs[16][64];
  int t = threadIdx.x;
  int row0 = blockIdx.x * 16;
  ((float4*)xs)[t] = ((const float4*)x)[(size_t)row0 * 16 + t];
  __syncthreads();
  int tx = t & 31, ty = t >> 5;  // ty: rows ty and ty+8
  const float4* W0_4 = (const float4*)W0;
  const float4* W1_4 = (const float4*)W1;
  float4 a00 = {0, 0, 0, 0}, a01 = {0, 0, 0, 0}, a10 = {0, 0, 0, 0}, a11 = {0, 0, 0, 0};
#pragma unroll 8
  for (int k = 0; k < 64; ++k) {
    float xv0 = xs[ty][k];
    float xv1 = xs[ty + 8][k];
    float4 w0 = W0_4[k * 32 + tx];
    float4 w1 = W1_4[k * 32 + tx];
    fma4(a00, xv0, w0); fma4(a01, xv1, w0);
    fma4(a10, xv0, w1); fma4(a11, xv1, w1);
  }
  float4 bb0 = ((const float4*)b0)[tx];
  float4 bb1 = ((const float4*)b1)[tx];
  fma4(a00, 1.f, bb0); fma4(a01, 1.f, bb0);
  fma4(a10, 1.f, bb1); fma4(a11, 1.f, bb1);
  auto pack = [](const float4& v) {
    uint2 p;
    p.x = (unsigned)f2bf(v.x) | ((unsigned)f2bf(v.y) << 16);
    p.y = (unsigned)f2bf(v.z) | ((unsigned)f2bf(v.w) << 16);
    return p;
  };
  size_t r0 = (size_t)(row0 + ty) * 64;
  size_t r1 = (size_t)(row0 + ty + 8) * 64;
  out[r0 + tx] = pack(a00);
  out[r0 + 32 + tx] = pack(a10);
  out[r1 + tx] = pack(a01);
  out[r1 + 32 + tx] = pack(a11);
}

// ===================== H x H GEMM, LDS-tiled =============================
// out[N,128] = act(x[N,128] @ W[128,128] + b); 32 rows/block, 16 acc/thread
template <bool PRELU>
__global__ __launch_bounds__(256) void gemm_hh2(const float* __restrict__ x,
                                                const float* __restrict__ W,
                                                const float* __restrict__ b,
                                                const float* __restrict__ alpha,
                                                float* __restrict__ out) {
  __shared__ float As[32 * 36];   // [k][m], padded
  __shared__ float Ws[32 * 128];  // [k][n]
  int t = threadIdx.x;
  int tx = t & 31, ty = t >> 5;  // cols 4tx.., rows ty*4..
  int row0 = blockIdx.x * 32;
  float4 acc[4] = {{0, 0, 0, 0}, {0, 0, 0, 0}, {0, 0, 0, 0}, {0, 0, 0, 0}};
  const float4* Wg4 = (const float4*)W;
  for (int kt = 0; kt < 4; ++kt) {
    __syncthreads();
    {  // stage A tile transposed: As[k][m]
      int r = t >> 3;    // 0..31 (row within tile)
      int c4 = t & 7;    // 0..7  (float4 within 32-k slice)
      float4 av = ((const float4*)(x + (size_t)(row0 + r) * 128 + kt * 32))[c4];
      As[(c4 * 4 + 0) * 36 + r] = av.x;
      As[(c4 * 4 + 1) * 36 + r] = av.y;
      As[(c4 * 4 + 2) * 36 + r] = av.z;
      As[(c4 * 4 + 3) * 36 + r] = av.w;
    }
    {  // stage W tile: Ws[k][n]
#pragma unroll
      for (int j = 0; j < 4; ++j) {
        int idx = j * 256 + t;
        ((float4*)Ws)[idx] = Wg4[kt * 1024 + idx];
      }
    }
    __syncthreads();
#pragma unroll
    for (int k = 0; k < 32; ++k) {
      float4 am = *(const float4*)&As[k * 36 + ty * 4];
      float4 w4 = ((const float4*)Ws)[k * 32 + tx];
      fma4(acc[0], am.x, w4);
      fma4(acc[1], am.y, w4);
      fma4(acc[2], am.z, w4);
      fma4(acc[3], am.w, w4);
    }
  }
  float4 bb = ((const float4*)b)[tx];
  float al = PRELU ? alpha[0] : 0.f;
#pragma unroll
  for (int r = 0; r < 4; ++r) {
    float4 v = acc[r];
    v.x += bb.x; v.y += bb.y; v.z += bb.z; v.w += bb.w;
    if (PRELU) {
      v.x = v.x >= 0.f ? v.x : al * v.x;
      v.y = v.y >= 0.f ? v.y : al * v.y;
      v.z = v.z >= 0.f ? v.z : al * v.z;
      v.w = v.w >= 0.f ? v.w : al * v.w;
    }
    ((float4*)out)[(size_t)(row0 + ty * 4 + r) * 32 + tx] = v;
  }
}

// ============================ driver ====================================
extern "C" void kernel_launch(void* const* d_in, const int* in_sizes, int n_in,
                              void* d_out, int out_size, void* d_ws, size_t ws_size,
                              hipStream_t stream) {
  const float* x[3] = {(const float*)d_in[0], (const float*)d_in[1], (const float*)d_in[2]};
  const int* kr[5]; const int* kc[5]; const float* kv[5];  // a0,a1,a2,b1,b2
  for (int m = 0; m < 5; ++m) {
    kr[m] = (const int*)d_in[3 + 3 * m];
    kc[m] = (const int*)d_in[4 + 3 * m];
    kv[m] = (const float*)d_in[5 + 3 * m];
  }
  const float *W[2][3], *bv[2][3], *av[2][3];
  int idx = 18;
  for (int e = 0; e < 2; ++e)
    for (int d = 0; d < 3; ++d) {
      W[e][d] = (const float*)d_in[idx++];
      bv[e][d] = (const float*)d_in[idx++];
      av[e][d] = (const float*)d_in[idx++];
    }
  const float* pW1 = (const float*)d_in[36];
  const float* pb1 = (const float*)d_in[37];
  const float* alpha = (const float*)d_in[38];
  const float* pW2 = (const float*)d_in[39];
  const float* pb2 = (const float*)d_in[40];

  float* out = (float*)d_out;
  const size_t NH = (size_t)NCELL * HID;
  float* h_online = out;
  float* h_pred = out + NH;    // doubles as comb_e0 scratch until final GEMM
  float* h_target = out + 2 * NH;

  char* w = (char*)d_ws;
  auto carve = [&](size_t bytes) -> void* {
    void* p = (void*)w;
    w += (bytes + 255) & ~(size_t)255;
    return p;
  };
  int* rowp_g = (int*)carve((size_t)(T7 + 1) * 4);       // 2.8 MB
  int2* cv_g = (int2*)carve((size_t)7 * NNZE * 8);       // 44.8 MB (col,val pairs)
  int* counts = (int*)carve((size_t)T7 * 4);             // 2.8 MB
  int* cursor = (int*)carve((size_t)T7 * 4);             // 2.8 MB
  uint2* xt2 = (uint2*)carve((size_t)NCELL * 256 * 2);   // 51.2 MB (bf16)
  uint2* t2 = (uint2*)carve((size_t)NCELL * 256 * 2);    // 51.2 MB (bf16)
  float* comb1 = (float*)carve(NH * 4);                  // 51.2 MB (fp32, e1)
  int* bsum = (int*)carve(64 * 4);
  float* comb0 = h_pred;

  // structures: 0..2 = A_d (by r); 3/4 = B1 by r / by c; 5/6 = B2 by r / by c
  P7i skey = {{kr[0], kr[1], kr[2], kr[3], kc[3], kr[4], kc[4]}};
  P7i soth = {{kc[0], kc[1], kc[2], kc[3], kr[3], kc[4], kr[4]}};
  P7f sval = {{kv[0], kv[1], kv[2], kv[3], kv[3], kv[4], kv[4]}};

  hipMemsetAsync(counts, 0, (size_t)T7 * 4, stream);
  hist_all<<<dim3(3125, 7), 256, 0, stream>>>(skey, counts);
  scan_partial2<<<43, 256, 0, stream>>>(counts, bsum);
  scan_bsum<<<1, 64, 0, stream>>>(bsum, 43);
  scan_final2<<<43, 256, 0, stream>>>(counts, bsum, rowp_g, cursor);
  scatter_all<<<dim3(3125, 7), 256, 0, stream>>>(skey, soth, sval, cursor, cv_g);

  static const int nB[3] = {1, 2, 1};
  static const int BS[3][2] = {{3, -1}, {3, 5}, {5, -1}};
  for (int d = 0; d < 3; ++d) {
    gemm_nc2<<<6250, 256, 0, stream>>>(x[d], W[0][d], bv[0][d], W[1][d], bv[1][d], xt2);
    spmm256<1><<<25000, 256, 0, stream>>>(rowp_g + d * NCELL, cv_g, xt2,
                                          nullptr, (float4*)comb0, (float4*)comb1,
                                          nullptr, nullptr, nullptr, nullptr, 0);
    for (int bi = 0; bi < nB[d]; ++bi) {
      int sR = BS[d][bi];
      spmm256<0><<<25000, 256, 0, stream>>>(rowp_g + sR * NCELL, cv_g, xt2,
                                            t2, nullptr, nullptr,
                                            nullptr, nullptr, nullptr, nullptr, 0);
      if (bi == nB[d] - 1) {
        // final accumulate for this k-dim: fuse sigmoid gate + mean-write
        spmm256<3><<<25000, 256, 0, stream>>>(rowp_g + (sR + 1) * NCELL, cv_g, t2,
                                              nullptr, (float4*)comb0, (float4*)comb1,
                                              (const float4*)av[0][d], (const float4*)av[1][d],
                                              (float4*)h_online, (float4*)h_target,
                                              d == 0 ? 1 : 0);
      } else {
        spmm256<2><<<25000, 256, 0, stream>>>(rowp_g + (sR + 1) * NCELL, cv_g, t2,
                                              nullptr, (float4*)comb0, (float4*)comb1,
                                              nullptr, nullptr, nullptr, nullptr, 0);
      }
    }
  }

  float* tmpf = (float*)t2;  // t2 dead; reuse as fp32 [N,128]
  gemm_hh2<true><<<3125, 256, 0, stream>>>(h_online, pW1, pb1, alpha, tmpf);
  gemm_hh2<false><<<3125, 256, 0, stream>>>(tmpf, pW2, pb2, alpha, h_pred);
}

// Round 2
// 1922.628 us; speedup vs baseline: 1.1631x; 1.1504x over previous
//
#include <hip/hip_runtime.h>
#include <cstddef>

#define NCELL 100000
#define NNZE  800000
#define HID   128
#define CIN   64
#define T7    (7 * NCELL)
#define KPB   512                 // keys per bucket (power of 2)
#define NBKT  196                 // ceil(100000/512)
#define TOTB  (7 * NBKT)          // 1372 buckets total

struct P7i { const int* p[7]; };
struct P7f { const float* p[7]; };

__device__ __forceinline__ unsigned short f2bf(float f) {
  unsigned u = __float_as_uint(f);
  return (unsigned short)((u + 0x7fffu + ((u >> 16) & 1u)) >> 16);
}
__device__ __forceinline__ float bflo(unsigned x) { return __uint_as_float(x << 16); }
__device__ __forceinline__ float bfhi(unsigned x) { return __uint_as_float(x & 0xffff0000u); }
__device__ __forceinline__ void fma4(float4& a, float s, const float4& w) {
  a.x += s * w.x; a.y += s * w.y; a.z += s * w.z; a.w += s * w.w;
}

// ==================== 2-level counting sort (CSR build) =================
// Level 1: bin by key>>9 into 1372 buckets (writes append to ~88KB of hot
// lines -> full line utilization, no random-line RMW). Level 2: one block
// per bucket sorts its 512-key range via LDS hist+scan; rowp falls out of
// the local prefix; final (col,val) writes confined to a 32KB L2-hot range.

__global__ __launch_bounds__(256) void bhist(P7i keys, int* __restrict__ bhcnt) {
  __shared__ int h[NBKT];
  int s = blockIdx.y;
  int t = threadIdx.x;
  if (t < NBKT) h[t] = 0;
  __syncthreads();
  const int* kp = keys.p[s];
  for (int j = 0; j < 64; ++j) {
    int i = blockIdx.x * 16384 + j * 256 + t;
    if (i < NNZE) atomicAdd(&h[kp[i] >> 9], 1);
  }
  __syncthreads();
  if (t < NBKT && h[t]) atomicAdd(&bhcnt[s * NBKT + t], h[t]);
}

// exclusive scan of 1372 bucket counts; also seeds the padded cursors
__global__ __launch_bounds__(256) void bscan(const int* __restrict__ bh,
                                             int* __restrict__ boff,
                                             int* __restrict__ bcur,
                                             int* __restrict__ rowp) {
  __shared__ int ss[256];
  int t = threadIdx.x;
  int v[6];
  int s = 0;
  for (int j = 0; j < 6; ++j) {
    int idx = t * 6 + j;
    v[j] = s;
    s += (idx < TOTB) ? bh[idx] : 0;
  }
  ss[t] = s;
  __syncthreads();
  for (int off = 1; off < 256; off <<= 1) {
    int w = (t >= off) ? ss[t - off] : 0;
    __syncthreads();
    ss[t] += w;
    __syncthreads();
  }
  int excl = ss[t] - s;
  for (int j = 0; j < 6; ++j) {
    int idx = t * 6 + j;
    if (idx < TOTB) {
      int o = excl + v[j];
      boff[idx] = o;
      bcur[idx * 16] = o;  // stride-16 pad: no same-line atomic serialization
    }
  }
  if (t == 255) boff[TOTB] = ss[255];
  if (t == 0) rowp[T7] = 7 * NNZE;
}

// bin pass: payload packs val(32b) | oth(17b) | key_local(9b) into uint2
__global__ __launch_bounds__(256) void sortA(P7i keys, P7i oth, P7f vs,
                                             int* __restrict__ bcur,
                                             uint2* __restrict__ tmp) {
  int s = blockIdx.y;
  int t = threadIdx.x;
  const int* kp = keys.p[s];
  const int* op = oth.p[s];
  const float* vp = vs.p[s];
  for (int j = 0; j < 64; ++j) {
    int i = blockIdx.x * 16384 + j * 256 + t;
    if (i < NNZE) {
      int k = kp[i];
      int b = k >> 9;
      int pos = atomicAdd(&bcur[(s * NBKT + b) * 16], 1);
      unsigned hi = (unsigned)op[i] | ((unsigned)(k & 511) << 17);
      tmp[pos] = make_uint2((unsigned)__float_as_int(vp[i]), hi);
    }
  }
}

// per-bucket sort: LDS hist -> scan -> rowp -> LDS-cursor scatter
__global__ __launch_bounds__(256) void sortB(const uint2* __restrict__ tmp,
                                             const int* __restrict__ boff,
                                             int* __restrict__ rowp,
                                             int2* __restrict__ cv) {
  __shared__ int hist[KPB];
  __shared__ int ss[256];
  int t = threadIdx.x;
  int b = blockIdx.x, s = blockIdx.y;
  int tb = s * NBKT + b;
  int base = boff[tb];
  int cnt = boff[tb + 1] - base;
  int key0 = b * KPB;
  int nk = NCELL - key0; if (nk > KPB) nk = KPB;
  hist[t] = 0;
  hist[t + 256] = 0;
  __syncthreads();
  for (int i = t; i < cnt; i += 256)
    atomicAdd(&hist[tmp[base + i].y >> 17], 1);
  __syncthreads();
  int a0 = hist[2 * t], a1 = hist[2 * t + 1];
  int sum = a0 + a1;
  ss[t] = sum;
  __syncthreads();
  for (int off = 1; off < 256; off <<= 1) {
    int w = (t >= off) ? ss[t - off] : 0;
    __syncthreads();
    ss[t] += w;
    __syncthreads();
  }
  int excl = ss[t] - sum;
  hist[2 * t] = excl;
  hist[2 * t + 1] = excl + a0;
  __syncthreads();
  for (int k = t; k < nk; k += 256)
    rowp[s * NCELL + key0 + k] = base + hist[k];
  __syncthreads();
  for (int i = t; i < cnt; i += 256) {
    uint2 u = tmp[base + i];
    int k = u.y >> 17;
    int pos = atomicAdd(&hist[k], 1);
    cv[base + pos] = make_int2((int)(u.y & 0x1FFFFu), (int)u.x);
  }
}

// ============================ SpMM width-256 (bf16 gathers) =============
// one wave per row; lane owns 4 bf16 cols (8B). MODE: 0=write bf16 outT,
// 1=write fp32 comb split by encoder, 2=accumulate 0.5x into comb split,
// 3=final accumulate + fused sigmoid gate + mean-write into h buffers.
template <int MODE>
__global__ __launch_bounds__(256) void spmm256(const int* __restrict__ rowp,
                                               const int2* __restrict__ cv,
                                               const uint2* __restrict__ xb,
                                               uint2* __restrict__ outT,
                                               float4* __restrict__ c0,
                                               float4* __restrict__ c1,
                                               const float4* __restrict__ g0p,
                                               const float4* __restrict__ g1p,
                                               float4* __restrict__ hon,
                                               float4* __restrict__ htg,
                                               int first) {
  int wid = (blockIdx.x * 256 + threadIdx.x) >> 6;
  int lane = threadIdx.x & 63;
  int s = rowp[wid], e = rowp[wid + 1];
  float a0 = 0.f, a1 = 0.f, a2 = 0.f, a3 = 0.f;
  int i = s;
  for (; i + 4 <= e; i += 4) {
    int2 p0 = cv[i], p1 = cv[i + 1], p2 = cv[i + 2], p3 = cv[i + 3];
    float v0 = __int_as_float(p0.y), v1 = __int_as_float(p1.y);
    float v2 = __int_as_float(p2.y), v3 = __int_as_float(p3.y);
    uint2 g0 = xb[(size_t)p0.x * 64 + lane];
    uint2 g1 = xb[(size_t)p1.x * 64 + lane];
    uint2 g2 = xb[(size_t)p2.x * 64 + lane];
    uint2 g3 = xb[(size_t)p3.x * 64 + lane];
    a0 += v0 * bflo(g0.x); a1 += v0 * bfhi(g0.x); a2 += v0 * bflo(g0.y); a3 += v0 * bfhi(g0.y);
    a0 += v1 * bflo(g1.x); a1 += v1 * bfhi(g1.x); a2 += v1 * bflo(g1.y); a3 += v1 * bfhi(g1.y);
    a0 += v2 * bflo(g2.x); a1 += v2 * bfhi(g2.x); a2 += v2 * bflo(g2.y); a3 += v2 * bfhi(g2.y);
    a0 += v3 * bflo(g3.x); a1 += v3 * bfhi(g3.x); a2 += v3 * bflo(g3.y); a3 += v3 * bfhi(g3.y);
  }
  for (; i < e; ++i) {
    int2 p = cv[i];
    float v = __int_as_float(p.y);
    uint2 g = xb[(size_t)p.x * 64 + lane];
    a0 += v * bflo(g.x); a1 += v * bfhi(g.x); a2 += v * bflo(g.y); a3 += v * bfhi(g.y);
  }
  if (MODE == 0) {
    uint2 pk;
    pk.x = (unsigned)f2bf(a0) | ((unsigned)f2bf(a1) << 16);
    pk.y = (unsigned)f2bf(a2) | ((unsigned)f2bf(a3) << 16);
    outT[(size_t)wid * 64 + lane] = pk;
  } else if (MODE == 1 || MODE == 2) {
    float4 v = make_float4(a0, a1, a2, a3);
    float4* dst = (lane < 32) ? (c0 + (size_t)wid * 32 + lane)
                              : (c1 + (size_t)wid * 32 + (lane - 32));
    if (MODE == 1) {
      *dst = v;
    } else {
      float4 cur = *dst;
      cur.x += 0.5f * v.x; cur.y += 0.5f * v.y;
      cur.z += 0.5f * v.z; cur.w += 0.5f * v.w;
      *dst = cur;
    }
  } else {  // MODE 3: final accumulate + gate, comb never written back
    bool e1 = lane >= 32;
    int l = lane & 31;
    const float4* cb = e1 ? c1 : c0;
    float4 cur = cb[(size_t)wid * 32 + l];
    cur.x += 0.5f * a0; cur.y += 0.5f * a1;
    cur.z += 0.5f * a2; cur.w += 0.5f * a3;
    float4 avv = (e1 ? g1p : g0p)[l];
    float d = cur.x * avv.x + cur.y * avv.y + cur.z * avv.z + cur.w * avv.w;
    d += __shfl_xor(d, 16);
    d += __shfl_xor(d, 8);
    d += __shfl_xor(d, 4);
    d += __shfl_xor(d, 2);
    d += __shfl_xor(d, 1);
    float g = (1.f / (1.f + __expf(-d))) * (1.f / 3.f);
    float4* hb = e1 ? htg : hon;
    size_t oi = (size_t)wid * 32 + l;
    float4 v = make_float4(g * cur.x, g * cur.y, g * cur.z, g * cur.w);
    if (first) {
      hb[oi] = v;
    } else {
      float4 c = hb[oi];
      c.x += v.x; c.y += v.y; c.z += v.z; c.w += v.w;
      hb[oi] = c;
    }
  }
}

// ===================== fused input GEMM (both encoders) =================
// xt2[n][256] (bf16) = [ x[n]@W0+b0 | x[n]@W1+b1 ] ; 16 rows/block
__global__ __launch_bounds__(256) void gemm_nc2(const float* __restrict__ x,
                                                const float* __restrict__ W0,
                                                const float* __restrict__ b0,
                                                const float* __restrict__ W1,
                                                const float* __restrict__ b1,
                                                uint2* __restrict__ out) {
  __shared__ float xs[16][64];
  int t = threadIdx.x;
  int row0 = blockIdx.x * 16;
  ((float4*)xs)[t] = ((const float4*)x)[(size_t)row0 * 16 + t];
  __syncthreads();
  int tx = t & 31, ty = t >> 5;  // ty: rows ty and ty+8
  const float4* W0_4 = (const float4*)W0;
  const float4* W1_4 = (const float4*)W1;
  float4 a00 = {0, 0, 0, 0}, a01 = {0, 0, 0, 0}, a10 = {0, 0, 0, 0}, a11 = {0, 0, 0, 0};
#pragma unroll 8
  for (int k = 0; k < 64; ++k) {
    float xv0 = xs[ty][k];
    float xv1 = xs[ty + 8][k];
    float4 w0 = W0_4[k * 32 + tx];
    float4 w1 = W1_4[k * 32 + tx];
    fma4(a00, xv0, w0); fma4(a01, xv1, w0);
    fma4(a10, xv0, w1); fma4(a11, xv1, w1);
  }
  float4 bb0 = ((const float4*)b0)[tx];
  float4 bb1 = ((const float4*)b1)[tx];
  fma4(a00, 1.f, bb0); fma4(a01, 1.f, bb0);
  fma4(a10, 1.f, bb1); fma4(a11, 1.f, bb1);
  auto pack = [](const float4& v) {
    uint2 p;
    p.x = (unsigned)f2bf(v.x) | ((unsigned)f2bf(v.y) << 16);
    p.y = (unsigned)f2bf(v.z) | ((unsigned)f2bf(v.w) << 16);
    return p;
  };
  size_t r0 = (size_t)(row0 + ty) * 64;
  size_t r1 = (size_t)(row0 + ty + 8) * 64;
  out[r0 + tx] = pack(a00);
  out[r0 + 32 + tx] = pack(a10);
  out[r1 + tx] = pack(a01);
  out[r1 + 32 + tx] = pack(a11);
}

// ===================== H x H GEMM, LDS-tiled =============================
// out[N,128] = act(x[N,128] @ W[128,128] + b); 32 rows/block, 16 acc/thread
template <bool PRELU>
__global__ __launch_bounds__(256) void gemm_hh2(const float* __restrict__ x,
                                                const float* __restrict__ W,
                                                const float* __restrict__ b,
                                                const float* __restrict__ alpha,
                                                float* __restrict__ out) {
  __shared__ float As[32 * 36];   // [k][m], padded
  __shared__ float Ws[32 * 128];  // [k][n]
  int t = threadIdx.x;
  int tx = t & 31, ty = t >> 5;  // cols 4tx.., rows ty*4..
  int row0 = blockIdx.x * 32;
  float4 acc[4] = {{0, 0, 0, 0}, {0, 0, 0, 0}, {0, 0, 0, 0}, {0, 0, 0, 0}};
  const float4* Wg4 = (const float4*)W;
  for (int kt = 0; kt < 4; ++kt) {
    __syncthreads();
    {  // stage A tile transposed: As[k][m]
      int r = t >> 3;    // 0..31 (row within tile)
      int c4 = t & 7;    // 0..7  (float4 within 32-k slice)
      float4 av = ((const float4*)(x + (size_t)(row0 + r) * 128 + kt * 32))[c4];
      As[(c4 * 4 + 0) * 36 + r] = av.x;
      As[(c4 * 4 + 1) * 36 + r] = av.y;
      As[(c4 * 4 + 2) * 36 + r] = av.z;
      As[(c4 * 4 + 3) * 36 + r] = av.w;
    }
    {  // stage W tile: Ws[k][n]
#pragma unroll
      for (int j = 0; j < 4; ++j) {
        int idx = j * 256 + t;
        ((float4*)Ws)[idx] = Wg4[kt * 1024 + idx];
      }
    }
    __syncthreads();
#pragma unroll
    for (int k = 0; k < 32; ++k) {
      float4 am = *(const float4*)&As[k * 36 + ty * 4];
      float4 w4 = ((const float4*)Ws)[k * 32 + tx];
      fma4(acc[0], am.x, w4);
      fma4(acc[1], am.y, w4);
      fma4(acc[2], am.z, w4);
      fma4(acc[3], am.w, w4);
    }
  }
  float4 bb = ((const float4*)b)[tx];
  float al = PRELU ? alpha[0] : 0.f;
#pragma unroll
  for (int r = 0; r < 4; ++r) {
    float4 v = acc[r];
    v.x += bb.x; v.y += bb.y; v.z += bb.z; v.w += bb.w;
    if (PRELU) {
      v.x = v.x >= 0.f ? v.x : al * v.x;
      v.y = v.y >= 0.f ? v.y : al * v.y;
      v.z = v.z >= 0.f ? v.z : al * v.z;
      v.w = v.w >= 0.f ? v.w : al * v.w;
    }
    ((float4*)out)[(size_t)(row0 + ty * 4 + r) * 32 + tx] = v;
  }
}

// ============================ driver ====================================
extern "C" void kernel_launch(void* const* d_in, const int* in_sizes, int n_in,
                              void* d_out, int out_size, void* d_ws, size_t ws_size,
                              hipStream_t stream) {
  const float* x[3] = {(const float*)d_in[0], (const float*)d_in[1], (const float*)d_in[2]};
  const int* kr[5]; const int* kc[5]; const float* kv[5];  // a0,a1,a2,b1,b2
  for (int m = 0; m < 5; ++m) {
    kr[m] = (const int*)d_in[3 + 3 * m];
    kc[m] = (const int*)d_in[4 + 3 * m];
    kv[m] = (const float*)d_in[5 + 3 * m];
  }
  const float *W[2][3], *bv[2][3], *av[2][3];
  int idx = 18;
  for (int e = 0; e < 2; ++e)
    for (int d = 0; d < 3; ++d) {
      W[e][d] = (const float*)d_in[idx++];
      bv[e][d] = (const float*)d_in[idx++];
      av[e][d] = (const float*)d_in[idx++];
    }
  const float* pW1 = (const float*)d_in[36];
  const float* pb1 = (const float*)d_in[37];
  const float* alpha = (const float*)d_in[38];
  const float* pW2 = (const float*)d_in[39];
  const float* pb2 = (const float*)d_in[40];

  float* out = (float*)d_out;
  const size_t NH = (size_t)NCELL * HID;
  float* h_online = out;
  float* h_pred = out + NH;    // doubles as comb_e0 scratch until final GEMM
  float* h_target = out + 2 * NH;

  char* w = (char*)d_ws;
  auto carve = [&](size_t bytes) -> void* {
    void* p = (void*)w;
    w += (bytes + 255) & ~(size_t)255;
    return p;
  };
  int* rowp_g = (int*)carve((size_t)(T7 + 1) * 4);       // 2.8 MB
  int2* cv_g = (int2*)carve((size_t)7 * NNZE * 8);       // 44.8 MB (col,val pairs)
  int* bhcnt = (int*)carve((size_t)TOTB * 4);            // 5.5 KB
  int* boff = (int*)carve((size_t)(TOTB + 1) * 4);       // 5.5 KB
  int* bcur = (int*)carve((size_t)TOTB * 16 * 4);        // 88 KB (padded cursors)
  uint2* xt2 = (uint2*)carve((size_t)NCELL * 256 * 2);   // 51.2 MB (bf16)
  uint2* t2 = (uint2*)carve((size_t)NCELL * 256 * 2);    // 51.2 MB (bf16)
  float* comb1 = (float*)carve(NH * 4);                  // 51.2 MB (fp32, e1)
  float* comb0 = h_pred;
  uint2* tmp = t2;  // bucket temp (44.8 MB); t2 dead until spmm phase

  // structures: 0..2 = A_d (by r); 3/4 = B1 by r / by c; 5/6 = B2 by r / by c
  P7i skey = {{kr[0], kr[1], kr[2], kr[3], kc[3], kr[4], kc[4]}};
  P7i soth = {{kc[0], kc[1], kc[2], kc[3], kr[3], kc[4], kr[4]}};
  P7f sval = {{kv[0], kv[1], kv[2], kv[3], kv[3], kv[4], kv[4]}};

  hipMemsetAsync(bhcnt, 0, (size_t)TOTB * 4, stream);
  bhist<<<dim3(49, 7), 256, 0, stream>>>(skey, bhcnt);
  bscan<<<1, 256, 0, stream>>>(bhcnt, boff, bcur, rowp_g);
  sortA<<<dim3(49, 7), 256, 0, stream>>>(skey, soth, sval, bcur, tmp);
  sortB<<<dim3(NBKT, 7), 256, 0, stream>>>(tmp, boff, rowp_g, cv_g);

  static const int nB[3] = {1, 2, 1};
  static const int BS[3][2] = {{3, -1}, {3, 5}, {5, -1}};
  for (int d = 0; d < 3; ++d) {
    gemm_nc2<<<6250, 256, 0, stream>>>(x[d], W[0][d], bv[0][d], W[1][d], bv[1][d], xt2);
    spmm256<1><<<25000, 256, 0, stream>>>(rowp_g + d * NCELL, cv_g, xt2,
                                          nullptr, (float4*)comb0, (float4*)comb1,
                                          nullptr, nullptr, nullptr, nullptr, 0);
    for (int bi = 0; bi < nB[d]; ++bi) {
      int sR = BS[d][bi];
      spmm256<0><<<25000, 256, 0, stream>>>(rowp_g + sR * NCELL, cv_g, xt2,
                                            t2, nullptr, nullptr,
                                            nullptr, nullptr, nullptr, nullptr, 0);
      if (bi == nB[d] - 1) {
        // final accumulate for this k-dim: fuse sigmoid gate + mean-write
        spmm256<3><<<25000, 256, 0, stream>>>(rowp_g + (sR + 1) * NCELL, cv_g, t2,
                                              nullptr, (float4*)comb0, (float4*)comb1,
                                              (const float4*)av[0][d], (const float4*)av[1][d],
                                              (float4*)h_online, (float4*)h_target,
                                              d == 0 ? 1 : 0);
      } else {
        spmm256<2><<<25000, 256, 0, stream>>>(rowp_g + (sR + 1) * NCELL, cv_g, t2,
                                              nullptr, (float4*)comb0, (float4*)comb1,
                                              nullptr, nullptr, nullptr, nullptr, 0);
      }
    }
  }

  float* tmpf = (float*)t2;  // t2 dead again; reuse as fp32 [N,128]
  gemm_hh2<true><<<3125, 256, 0, stream>>>(h_online, pW1, pb1, alpha, tmpf);
  gemm_hh2<false><<<3125, 256, 0, stream>>>(tmpf, pW2, pb2, alpha, h_pred);
}

// Round 4
// 1721.471 us; speedup vs baseline: 1.2991x; 1.1169x over previous
//
#include <hip/hip_runtime.h>
#include <cstddef>

#define NCELL 100000
#define NNZE  800000
#define HID   128
#define CIN   64
#define T7    (7 * NCELL)
#define KPB   512                 // keys per bucket (power of 2)
#define NBKT  196                 // ceil(100000/512)
#define TOTB  (7 * NBKT)          // 1372 buckets total
#define NBLK  49                  // partition blocks per structure (49*16384 >= 800000)

struct P7i { const int* p[7]; };
struct P7f { const float* p[7]; };

__device__ __forceinline__ unsigned short f2bf(float f) {
  unsigned u = __float_as_uint(f);
  return (unsigned short)((u + 0x7fffu + ((u >> 16) & 1u)) >> 16);
}
__device__ __forceinline__ float bflo(unsigned x) { return __uint_as_float(x << 16); }
__device__ __forceinline__ float bfhi(unsigned x) { return __uint_as_float(x & 0xffff0000u); }
__device__ __forceinline__ void fma4(float4& a, float s, const float4& w) {
  a.x += s * w.x; a.y += s * w.y; a.z += s * w.z; a.w += s * w.w;
}

// ==================== deterministic radix partition (CSR build) =========
// Pass 1: per-block LDS histogram -> bh[(s*196+b)*49+blk] (no global atomics).
// Pass 2: single-block exclusive scan over all 67228 counts (in place).
// Pass 3: bucket base offsets + rowp tail.
// Pass 4: scatter; each block writes contiguous per-bucket runs (~680B) into
// precomputed private windows -> full-line merge in its own XCD's L2.
// Pass 5 (sortB): per-bucket LDS counting sort by full key -> rowp + cv.

__global__ __launch_bounds__(256) void phist(P7i keys, int* __restrict__ bh) {
  __shared__ int h[NBKT];
  int s = blockIdx.y, blk = blockIdx.x, t = threadIdx.x;
  if (t < NBKT) h[t] = 0;
  __syncthreads();
  const int* kp = keys.p[s];
  for (int j = 0; j < 64; ++j) {
    int i = blk * 16384 + j * 256 + t;
    if (i < NNZE) atomicAdd(&h[kp[i] >> 9], 1);
  }
  __syncthreads();
  if (t < NBKT) bh[(s * NBKT + t) * NBLK + blk] = h[t];
}

__global__ __launch_bounds__(256) void pscan(int* __restrict__ bh) {
  __shared__ int ss[256];
  const int n = TOTB * NBLK;  // 67228
  const int CH = 263;         // 263*256 = 67328 >= n
  int t = threadIdx.x;
  int base = t * CH;
  int s = 0;
  for (int j = 0; j < CH; ++j) {
    int idx = base + j;
    if (idx < n) s += bh[idx];
  }
  ss[t] = s;
  __syncthreads();
  for (int off = 1; off < 256; off <<= 1) {
    int w = (t >= off) ? ss[t - off] : 0;
    __syncthreads();
    ss[t] += w;
    __syncthreads();
  }
  int run = ss[t] - s;  // exclusive base for this thread's chunk
  for (int j = 0; j < CH; ++j) {
    int idx = base + j;
    if (idx < n) {
      int v = bh[idx];
      bh[idx] = run;
      run += v;
    }
  }
}

__global__ __launch_bounds__(256) void pboff(const int* __restrict__ bofs,
                                             int* __restrict__ boff,
                                             int* __restrict__ rowp) {
  int i = blockIdx.x * 256 + threadIdx.x;
  if (i < TOTB) boff[i] = bofs[i * NBLK];
  if (i == 0) {
    boff[TOTB] = 7 * NNZE;
    rowp[T7] = 7 * NNZE;
  }
}

// payload packs val(32b) | oth(17b) | key_local(9b)
__global__ __launch_bounds__(256) void pscatter(P7i keys, P7i oth, P7f vs,
                                                const int* __restrict__ bofs,
                                                uint2* __restrict__ tmp) {
  __shared__ int cur[NBKT];
  int s = blockIdx.y, blk = blockIdx.x, t = threadIdx.x;
  if (t < NBKT) cur[t] = bofs[(s * NBKT + t) * NBLK + blk];
  __syncthreads();
  const int* kp = keys.p[s];
  const int* op = oth.p[s];
  const float* vp = vs.p[s];
  for (int j = 0; j < 64; ++j) {
    int i = blk * 16384 + j * 256 + t;
    if (i < NNZE) {
      int k = kp[i];
      int pos = atomicAdd(&cur[k >> 9], 1);
      tmp[pos] = make_uint2((unsigned)__float_as_int(vp[i]),
                            (unsigned)op[i] | ((unsigned)(k & 511) << 17));
    }
  }
}

// per-bucket sort: LDS hist -> scan -> rowp -> LDS-cursor scatter
__global__ __launch_bounds__(256) void sortB(const uint2* __restrict__ tmp,
                                             const int* __restrict__ boff,
                                             int* __restrict__ rowp,
                                             int2* __restrict__ cv) {
  __shared__ int hist[KPB];
  __shared__ int ss[256];
  int t = threadIdx.x;
  int b = blockIdx.x, s = blockIdx.y;
  int tb = s * NBKT + b;
  int base = boff[tb];
  int cnt = boff[tb + 1] - base;
  int key0 = b * KPB;
  int nk = NCELL - key0; if (nk > KPB) nk = KPB;
  hist[t] = 0;
  hist[t + 256] = 0;
  __syncthreads();
  for (int i = t; i < cnt; i += 256)
    atomicAdd(&hist[tmp[base + i].y >> 17], 1);
  __syncthreads();
  int a0 = hist[2 * t], a1 = hist[2 * t + 1];
  int sum = a0 + a1;
  ss[t] = sum;
  __syncthreads();
  for (int off = 1; off < 256; off <<= 1) {
    int w = (t >= off) ? ss[t - off] : 0;
    __syncthreads();
    ss[t] += w;
    __syncthreads();
  }
  int excl = ss[t] - sum;
  hist[2 * t] = excl;
  hist[2 * t + 1] = excl + a0;
  __syncthreads();
  for (int k = t; k < nk; k += 256)
    rowp[s * NCELL + key0 + k] = base + hist[k];
  __syncthreads();
  for (int i = t; i < cnt; i += 256) {
    uint2 u = tmp[base + i];
    int k = u.y >> 17;
    int pos = atomicAdd(&hist[k], 1);
    cv[base + pos] = make_int2((int)(u.y & 0x1FFFFu), (int)u.x);
  }
}

// ============================ SpMM gathers (bf16) =======================
// one wave per row; lane owns 4 bf16 cols (8B of the 512B row).
__device__ __forceinline__ void gather4(const int* __restrict__ rowp, int wid, int lane,
                                        const int2* __restrict__ cv,
                                        const uint2* __restrict__ xb, float wgt,
                                        float& a0, float& a1, float& a2, float& a3) {
  int s = rowp[wid], e = rowp[wid + 1];
  int i = s;
  for (; i + 4 <= e; i += 4) {
    int2 p0 = cv[i], p1 = cv[i + 1], p2 = cv[i + 2], p3 = cv[i + 3];
    float v0 = wgt * __int_as_float(p0.y), v1 = wgt * __int_as_float(p1.y);
    float v2 = wgt * __int_as_float(p2.y), v3 = wgt * __int_as_float(p3.y);
    uint2 g0 = xb[(size_t)p0.x * 64 + lane];
    uint2 g1 = xb[(size_t)p1.x * 64 + lane];
    uint2 g2 = xb[(size_t)p2.x * 64 + lane];
    uint2 g3 = xb[(size_t)p3.x * 64 + lane];
    a0 += v0 * bflo(g0.x); a1 += v0 * bfhi(g0.x); a2 += v0 * bflo(g0.y); a3 += v0 * bfhi(g0.y);
    a0 += v1 * bflo(g1.x); a1 += v1 * bfhi(g1.x); a2 += v1 * bflo(g1.y); a3 += v1 * bfhi(g1.y);
    a0 += v2 * bflo(g2.x); a1 += v2 * bfhi(g2.x); a2 += v2 * bflo(g2.y); a3 += v2 * bfhi(g2.y);
    a0 += v3 * bflo(g3.x); a1 += v3 * bfhi(g3.x); a2 += v3 * bflo(g3.y); a3 += v3 * bfhi(g3.y);
  }
  for (; i < e; ++i) {
    int2 p = cv[i];
    float v = wgt * __int_as_float(p.y);
    uint2 g = xb[(size_t)p.x * 64 + lane];
    a0 += v * bflo(g.x); a1 += v * bfhi(g.x); a2 += v * bflo(g.y); a3 += v * bfhi(g.y);
  }
}

// chain pass 1: y = B @ xt, packed bf16
__global__ __launch_bounds__(256) void spmm_b(const int* __restrict__ rowp,
                                              const int2* __restrict__ cv,
                                              const uint2* __restrict__ xb,
                                              uint2* __restrict__ outT) {
  int wid = (blockIdx.x * 256 + threadIdx.x) >> 6;
  int lane = threadIdx.x & 63;
  float a0 = 0.f, a1 = 0.f, a2 = 0.f, a3 = 0.f;
  gather4(rowp, wid, lane, cv, xb, 1.f, a0, a1, a2, a3);
  uint2 pk;
  pk.x = (unsigned)f2bf(a0) | ((unsigned)f2bf(a1) << 16);
  pk.y = (unsigned)f2bf(a2) | ((unsigned)f2bf(a3) << 16);
  outT[(size_t)wid * 64 + lane] = pk;
}

// mega: comb = A@xt + 0.5*B0^T y0 (+ 0.5*B1^T y1) in registers, then
// fused sigmoid gate + mean accumulate into h_online / h_target.
template <int NCHAIN>
__global__ __launch_bounds__(256) void spmm_mega(const int* __restrict__ rowpA,
                                                 const int* __restrict__ rowpT0,
                                                 const int* __restrict__ rowpT1,
                                                 const int2* __restrict__ cv,
                                                 const uint2* __restrict__ xb,
                                                 const uint2* __restrict__ t0,
                                                 const uint2* __restrict__ t1,
                                                 const float4* __restrict__ g0p,
                                                 const float4* __restrict__ g1p,
                                                 float4* __restrict__ hon,
                                                 float4* __restrict__ htg,
                                                 int first) {
  int wid = (blockIdx.x * 256 + threadIdx.x) >> 6;
  int lane = threadIdx.x & 63;
  float a0 = 0.f, a1 = 0.f, a2 = 0.f, a3 = 0.f;
  gather4(rowpA, wid, lane, cv, xb, 1.f, a0, a1, a2, a3);
  gather4(rowpT0, wid, lane, cv, t0, 0.5f, a0, a1, a2, a3);
  if (NCHAIN == 2) gather4(rowpT1, wid, lane, cv, t1, 0.5f, a0, a1, a2, a3);

  bool e1 = lane >= 32;
  int l = lane & 31;
  float4 avv = (e1 ? g1p : g0p)[l];
  float d = a0 * avv.x + a1 * avv.y + a2 * avv.z + a3 * avv.w;
  d += __shfl_xor(d, 16);
  d += __shfl_xor(d, 8);
  d += __shfl_xor(d, 4);
  d += __shfl_xor(d, 2);
  d += __shfl_xor(d, 1);
  float g = (1.f / (1.f + __expf(-d))) * (1.f / 3.f);
  float4* hb = e1 ? htg : hon;
  size_t oi = (size_t)wid * 32 + l;
  float4 v = make_float4(g * a0, g * a1, g * a2, g * a3);
  if (first) {
    hb[oi] = v;
  } else {
    float4 c = hb[oi];
    c.x += v.x; c.y += v.y; c.z += v.z; c.w += v.w;
    hb[oi] = c;
  }
}

// ===================== fused input GEMM (both encoders) =================
// xt2[n][256] (bf16) = [ x[n]@W0+b0 | x[n]@W1+b1 ] ; 16 rows/block
__global__ __launch_bounds__(256) void gemm_nc2(const float* __restrict__ x,
                                                const float* __restrict__ W0,
                                                const float* __restrict__ b0,
                                                const float* __restrict__ W1,
                                                const float* __restrict__ b1,
                                                uint2* __restrict__ out) {
  __shared__ float xs[16][64];
  int t = threadIdx.x;
  int row0 = blockIdx.x * 16;
  ((float4*)xs)[t] = ((const float4*)x)[(size_t)row0 * 16 + t];
  __syncthreads();
  int tx = t & 31, ty = t >> 5;  // ty: rows ty and ty+8
  const float4* W0_4 = (const float4*)W0;
  const float4* W1_4 = (const float4*)W1;
  float4 a00 = {0, 0, 0, 0}, a01 = {0, 0, 0, 0}, a10 = {0, 0, 0, 0}, a11 = {0, 0, 0, 0};
#pragma unroll 8
  for (int k = 0; k < 64; ++k) {
    float xv0 = xs[ty][k];
    float xv1 = xs[ty + 8][k];
    float4 w0 = W0_4[k * 32 + tx];
    float4 w1 = W1_4[k * 32 + tx];
    fma4(a00, xv0, w0); fma4(a01, xv1, w0);
    fma4(a10, xv0, w1); fma4(a11, xv1, w1);
  }
  float4 bb0 = ((const float4*)b0)[tx];
  float4 bb1 = ((const float4*)b1)[tx];
  fma4(a00, 1.f, bb0); fma4(a01, 1.f, bb0);
  fma4(a10, 1.f, bb1); fma4(a11, 1.f, bb1);
  auto pack = [](const float4& v) {
    uint2 p;
    p.x = (unsigned)f2bf(v.x) | ((unsigned)f2bf(v.y) << 16);
    p.y = (unsigned)f2bf(v.z) | ((unsigned)f2bf(v.w) << 16);
    return p;
  };
  size_t r0 = (size_t)(row0 + ty) * 64;
  size_t r1 = (size_t)(row0 + ty + 8) * 64;
  out[r0 + tx] = pack(a00);
  out[r0 + 32 + tx] = pack(a10);
  out[r1 + tx] = pack(a01);
  out[r1 + 32 + tx] = pack(a11);
}

// ===================== H x H GEMM, LDS-tiled =============================
// out[N,128] = act(x[N,128] @ W[128,128] + b); 32 rows/block, 16 acc/thread
template <bool PRELU>
__global__ __launch_bounds__(256) void gemm_hh2(const float* __restrict__ x,
                                                const float* __restrict__ W,
                                                const float* __restrict__ b,
                                                const float* __restrict__ alpha,
                                                float* __restrict__ out) {
  __shared__ float As[32 * 36];   // [k][m], padded
  __shared__ float Ws[32 * 128];  // [k][n]
  int t = threadIdx.x;
  int tx = t & 31, ty = t >> 5;  // cols 4tx.., rows ty*4..
  int row0 = blockIdx.x * 32;
  float4 acc[4] = {{0, 0, 0, 0}, {0, 0, 0, 0}, {0, 0, 0, 0}, {0, 0, 0, 0}};
  const float4* Wg4 = (const float4*)W;
  for (int kt = 0; kt < 4; ++kt) {
    __syncthreads();
    {  // stage A tile transposed: As[k][m]
      int r = t >> 3;    // 0..31 (row within tile)
      int c4 = t & 7;    // 0..7  (float4 within 32-k slice)
      float4 av = ((const float4*)(x + (size_t)(row0 + r) * 128 + kt * 32))[c4];
      As[(c4 * 4 + 0) * 36 + r] = av.x;
      As[(c4 * 4 + 1) * 36 + r] = av.y;
      As[(c4 * 4 + 2) * 36 + r] = av.z;
      As[(c4 * 4 + 3) * 36 + r] = av.w;
    }
    {  // stage W tile: Ws[k][n]
#pragma unroll
      for (int j = 0; j < 4; ++j) {
        int idx = j * 256 + t;
        ((float4*)Ws)[idx] = Wg4[kt * 1024 + idx];
      }
    }
    __syncthreads();
#pragma unroll
    for (int k = 0; k < 32; ++k) {
      float4 am = *(const float4*)&As[k * 36 + ty * 4];
      float4 w4 = ((const float4*)Ws)[k * 32 + tx];
      fma4(acc[0], am.x, w4);
      fma4(acc[1], am.y, w4);
      fma4(acc[2], am.z, w4);
      fma4(acc[3], am.w, w4);
    }
  }
  float4 bb = ((const float4*)b)[tx];
  float al = PRELU ? alpha[0] : 0.f;
#pragma unroll
  for (int r = 0; r < 4; ++r) {
    float4 v = acc[r];
    v.x += bb.x; v.y += bb.y; v.z += bb.z; v.w += bb.w;
    if (PRELU) {
      v.x = v.x >= 0.f ? v.x : al * v.x;
      v.y = v.y >= 0.f ? v.y : al * v.y;
      v.z = v.z >= 0.f ? v.z : al * v.z;
      v.w = v.w >= 0.f ? v.w : al * v.w;
    }
    ((float4*)out)[(size_t)(row0 + ty * 4 + r) * 32 + tx] = v;
  }
}

// ============================ driver ====================================
extern "C" void kernel_launch(void* const* d_in, const int* in_sizes, int n_in,
                              void* d_out, int out_size, void* d_ws, size_t ws_size,
                              hipStream_t stream) {
  const float* x[3] = {(const float*)d_in[0], (const float*)d_in[1], (const float*)d_in[2]};
  const int* kr[5]; const int* kc[5]; const float* kv[5];  // a0,a1,a2,b1,b2
  for (int m = 0; m < 5; ++m) {
    kr[m] = (const int*)d_in[3 + 3 * m];
    kc[m] = (const int*)d_in[4 + 3 * m];
    kv[m] = (const float*)d_in[5 + 3 * m];
  }
  const float *W[2][3], *bv[2][3], *av[2][3];
  int idx = 18;
  for (int e = 0; e < 2; ++e)
    for (int d = 0; d < 3; ++d) {
      W[e][d] = (const float*)d_in[idx++];
      bv[e][d] = (const float*)d_in[idx++];
      av[e][d] = (const float*)d_in[idx++];
    }
  const float* pW1 = (const float*)d_in[36];
  const float* pb1 = (const float*)d_in[37];
  const float* alpha = (const float*)d_in[38];
  const float* pW2 = (const float*)d_in[39];
  const float* pb2 = (const float*)d_in[40];

  float* out = (float*)d_out;
  const size_t NH = (size_t)NCELL * HID;
  float* h_online = out;
  float* h_pred = out + NH;
  float* h_target = out + 2 * NH;

  char* w = (char*)d_ws;
  auto carve = [&](size_t bytes) -> void* {
    void* p = (void*)w;
    w += (bytes + 255) & ~(size_t)255;
    return p;
  };
  int* rowp_g = (int*)carve((size_t)(T7 + 1) * 4);       // 2.8 MB
  int2* cv_g = (int2*)carve((size_t)7 * NNZE * 8);       // 44.8 MB (col,val pairs)
  int* bh = (int*)carve((size_t)TOTB * NBLK * 4);        // 269 KB (per-block hists)
  int* boff = (int*)carve((size_t)(TOTB + 1) * 4);       // 5.5 KB
  uint2* xt2 = (uint2*)carve((size_t)NCELL * 256 * 2);   // 51.2 MB (bf16)
  uint2* t2a = (uint2*)carve((size_t)NCELL * 256 * 2);   // 51.2 MB (bf16)
  uint2* t2b = (uint2*)carve((size_t)NCELL * 256 * 2);   // 51.2 MB (bf16)
  uint2* tmp = t2a;  // radix temp (44.8 MB); t2a dead during sort phase

  // structures: 0..2 = A_d (by r); 3/4 = B1 by r / by c; 5/6 = B2 by r / by c
  P7i skey = {{kr[0], kr[1], kr[2], kr[3], kc[3], kr[4], kc[4]}};
  P7i soth = {{kc[0], kc[1], kc[2], kc[3], kr[3], kc[4], kr[4]}};
  P7f sval = {{kv[0], kv[1], kv[2], kv[3], kv[3], kv[4], kv[4]}};

  phist<<<dim3(NBLK, 7), 256, 0, stream>>>(skey, bh);
  pscan<<<1, 256, 0, stream>>>(bh);
  pboff<<<6, 256, 0, stream>>>(bh, boff, rowp_g);
  pscatter<<<dim3(NBLK, 7), 256, 0, stream>>>(skey, soth, sval, bh, tmp);
  sortB<<<dim3(NBKT, 7), 256, 0, stream>>>(tmp, boff, rowp_g, cv_g);

  // d = 0: comb = A0@xt + 0.5*B1^T(B1@xt)
  gemm_nc2<<<6250, 256, 0, stream>>>(x[0], W[0][0], bv[0][0], W[1][0], bv[1][0], xt2);
  spmm_b<<<25000, 256, 0, stream>>>(rowp_g + 3 * NCELL, cv_g, xt2, t2a);
  spmm_mega<1><<<25000, 256, 0, stream>>>(rowp_g + 0 * NCELL, rowp_g + 4 * NCELL, nullptr,
                                          cv_g, xt2, t2a, nullptr,
                                          (const float4*)av[0][0], (const float4*)av[1][0],
                                          (float4*)h_online, (float4*)h_target, 1);

  // d = 1: comb = A1@xt + 0.5*B1^T(B1@xt) + 0.5*B2^T(B2@xt)
  gemm_nc2<<<6250, 256, 0, stream>>>(x[1], W[0][1], bv[0][1], W[1][1], bv[1][1], xt2);
  spmm_b<<<25000, 256, 0, stream>>>(rowp_g + 3 * NCELL, cv_g, xt2, t2a);
  spmm_b<<<25000, 256, 0, stream>>>(rowp_g + 5 * NCELL, cv_g, xt2, t2b);
  spmm_mega<2><<<25000, 256, 0, stream>>>(rowp_g + 1 * NCELL, rowp_g + 4 * NCELL,
                                          rowp_g + 6 * NCELL, cv_g, xt2, t2a, t2b,
                                          (const float4*)av[0][1], (const float4*)av[1][1],
                                          (float4*)h_online, (float4*)h_target, 0);

  // d = 2: comb = A2@xt + 0.5*B2^T(B2@xt)
  gemm_nc2<<<6250, 256, 0, stream>>>(x[2], W[0][2], bv[0][2], W[1][2], bv[1][2], xt2);
  spmm_b<<<25000, 256, 0, stream>>>(rowp_g + 5 * NCELL, cv_g, xt2, t2a);
  spmm_mega<1><<<25000, 256, 0, stream>>>(rowp_g + 2 * NCELL, rowp_g + 6 * NCELL, nullptr,
                                          cv_g, xt2, t2a, nullptr,
                                          (const float4*)av[0][2], (const float4*)av[1][2],
                                          (float4*)h_online, (float4*)h_target, 0);

  float* tmpf = (float*)t2a;  // dead; reuse as fp32 [N,128]
  gemm_hh2<true><<<3125, 256, 0, stream>>>(h_online, pW1, pb1, alpha, tmpf);
  gemm_hh2<false><<<3125, 256, 0, stream>>>(tmpf, pW2, pb2, alpha, h_pred);
}